// Round 8
// baseline (332.146 us; speedup 1.0000x reference)
//
#include <hip/hip_runtime.h>
#include <hip/hip_bf16.h>
#include <math.h>

// ---------------------------------------------------------------------------
// Live computation (dead-code-eliminated reference):
//   dinv[v] = rsqrt(indeg(v)+1)
//   aggx    = A_norm @ x
//   h1s     = relu(aggx @ c1W + c1b) * dinv       (bf16)
//   aggh1   = A_norm @ h1
//   h2      = relu([aggh1, aggx] @ c2W + c2b)     (MFMA bf16, K padded to 160)
//   h4      = relu([x, h2] @ f4W + f4b)           (MFMA bf16)
//   out     = sigmoid([x, h4] @ f5W + f5b)        (fused into f4 epilogue)
// CSR build: bucket-by-XCD-range (ballot-packed, no atomic hist in stream
// pass); per-XCD histogram + fill so all cnt/cursor/col atomics stay in the
// owning XCD's L2 (no cross-XCD line ping-pong).
// ---------------------------------------------------------------------------

typedef __attribute__((ext_vector_type(8))) short short8;
typedef __attribute__((ext_vector_type(4))) float f32x4;

__device__ __forceinline__ unsigned short f32_to_bf16_rne(float f) {
    unsigned u = __float_as_uint(f);
    return (unsigned short)((u + 0x7fffu + ((u >> 16) & 1u)) >> 16);
}

// Phase 1: stream ei once; append (s,d) to bucket[part(d)] via wave ballot
// ranking (no LDS atomics, no global histogram — that is per-XCD in phase 1b).
__global__ __launch_bounds__(256) void bucket_kernel(
    const int* __restrict__ ei,
    int* __restrict__ bcnt, int2* __restrict__ bucket,
    int E, int N, int cap) {
    constexpr int EPB = 1024;          // 4 waves x 4 chunks x 64 lanes
    __shared__ int wcnt_s[4][8];
    __shared__ int wofs_s[4][8];
    __shared__ int lbase_s[8];

    int wave = threadIdx.x >> 6, lane = threadIdx.x & 63;
    unsigned long long ltmask = (lane == 63) ? 0x7fffffffffffffffull
                                             : ((1ull << lane) - 1ull);
    int ebase = blockIdx.x * EPB + wave * 256;

    int2 v[4];
    int  pv[4];
    int  wcnt[8];
#pragma unroll
    for (int P = 0; P < 8; P++) wcnt[P] = 0;

    // pass 1: load, classify, count (ballot)
#pragma unroll
    for (int c = 0; c < 4; c++) {
        int e = ebase + c * 64 + lane;
        pv[c] = 8;                                   // invalid sentinel
        if (e < E) {
            v[c] = ((const int2*)ei)[e];
            if ((unsigned)v[c].y < (unsigned)N) {
                pv[c] = (int)(((unsigned long long)(unsigned)v[c].y * 8ull)
                              / (unsigned)N);
                if ((unsigned)v[c].x >= (unsigned)N) v[c].x = 0;
            }
        }
#pragma unroll
        for (int P = 0; P < 8; P++)
            wcnt[P] += __popcll(__ballot(pv[c] == P));
    }

    if (lane == 0) {
#pragma unroll
        for (int P = 0; P < 8; P++) wcnt_s[wave][P] = wcnt[P];
    }
    __syncthreads();
    if (threadIdx.x < 8) {
        int P = threadIdx.x;
        int tot = 0;
#pragma unroll
        for (int w = 0; w < 4; w++) { wofs_s[w][P] = tot; tot += wcnt_s[w][P]; }
        lbase_s[P] = atomicAdd(&bcnt[P], tot);
    }
    __syncthreads();

    int woff[8];
#pragma unroll
    for (int P = 0; P < 8; P++) woff[P] = lbase_s[P] + wofs_s[wave][P];

    // pass 2: ballot-ranked scatter into buckets (contiguous per part/wave)
#pragma unroll
    for (int c = 0; c < 4; c++) {
#pragma unroll
        for (int P = 0; P < 8; P++) {
            unsigned long long m = __ballot(pv[c] == P);
            if (pv[c] == P) {
                int slot = woff[P] + __popcll(m & ltmask);
                if (slot < cap) bucket[(size_t)P * cap + slot] = v[c];
            }
            woff[P] += __popcll(m);
        }
    }
}

// Phase 1b: per-XCD histogram from own bucket; cnt slice (~50KB) stays in the
// owning XCD's L2 -> atomics never cross the coherence fabric.
__global__ __launch_bounds__(256) void hist2_kernel(
    const int2* __restrict__ bucket, const int* __restrict__ bcnt,
    int* __restrict__ cnt, int cap, int nchunk) {
    int p = blockIdx.x & 7;
    int c = blockIdx.x >> 3;
    int n = bcnt[p];
    if (n > cap) n = cap;
    const int2* b = bucket + (size_t)p * cap;
    int stride = nchunk * 256;
    for (int i = c * 256 + threadIdx.x; i < n; i += stride)
        atomicAdd(&cnt[b[i].y], 1);
}

// Phase 2: per-XCD CSR fill from own bucket (cursor+col L2-local).
__global__ __launch_bounds__(256) void fill2_kernel(
    const int2* __restrict__ bucket, const int* __restrict__ bcnt,
    int* __restrict__ cursor, int* __restrict__ col, int cap, int nchunk) {
    int p = blockIdx.x & 7;
    int c = blockIdx.x >> 3;
    int n = bcnt[p];
    if (n > cap) n = cap;
    const int2* b = bucket + (size_t)p * cap;
    int stride = nchunk * 256;
    for (int i = c * 256 + threadIdx.x; i < n; i += stride) {
        int2 v = b[i];
        int pos = atomicAdd(&cursor[v.y], 1);
        col[pos] = v.x;
    }
}

// dinv, xs (x*dinv f32), and Abf2 cols 0..7 = bf16(x) + zero tail cols 136..159
__global__ __launch_bounds__(256) void dinv_xs_kernel(const int* __restrict__ cnt,
                                                      const float* __restrict__ x,
                                                      float* __restrict__ dinv,
                                                      float* __restrict__ xs,
                                                      unsigned short* __restrict__ Abf2,
                                                      int n) {
    int v = blockIdx.x * 256 + threadIdx.x;
    if (v >= n) return;
    float dv = rsqrtf((float)(cnt[v] + 1));
    dinv[v] = dv;
    const float4* x4 = (const float4*)x;
    float4 a = x4[v * 2], b = x4[v * 2 + 1];
    float4* o = (float4*)xs;
    o[v * 2]     = make_float4(a.x * dv, a.y * dv, a.z * dv, a.w * dv);
    o[v * 2 + 1] = make_float4(b.x * dv, b.y * dv, b.z * dv, b.w * dv);
    unsigned short u[8] = {f32_to_bf16_rne(a.x), f32_to_bf16_rne(a.y),
                           f32_to_bf16_rne(a.z), f32_to_bf16_rne(a.w),
                           f32_to_bf16_rne(b.x), f32_to_bf16_rne(b.y),
                           f32_to_bf16_rne(b.z), f32_to_bf16_rne(b.w)};
    ulonglong2 pk;
    pk.x = (unsigned long long)u[0] | ((unsigned long long)u[1] << 16)
         | ((unsigned long long)u[2] << 32) | ((unsigned long long)u[3] << 48);
    pk.y = (unsigned long long)u[4] | ((unsigned long long)u[5] << 16)
         | ((unsigned long long)u[6] << 32) | ((unsigned long long)u[7] << 48);
    *(ulonglong2*)&Abf2[(size_t)v * 160] = pk;
    ulonglong2 z; z.x = 0ull; z.y = 0ull;
    *(ulonglong2*)&Abf2[(size_t)v * 160 + 136] = z;
    *(ulonglong2*)&Abf2[(size_t)v * 160 + 144] = z;
    *(ulonglong2*)&Abf2[(size_t)v * 160 + 152] = z;
}

// exclusive scan of cnt into rowptr
__global__ __launch_bounds__(1024) void scan1_kernel(const int* __restrict__ cnt,
                                                     int* __restrict__ rowptr,
                                                     int* __restrict__ bsum, int ntot, int N) {
    __shared__ int lds[1024];
    int i = blockIdx.x * 1024 + threadIdx.x;
    int v = (i < N) ? cnt[i] : 0;
    lds[threadIdx.x] = v;
    __syncthreads();
    for (int off = 1; off < 1024; off <<= 1) {
        int y = (threadIdx.x >= off) ? lds[threadIdx.x - off] : 0;
        __syncthreads();
        if (threadIdx.x >= off) lds[threadIdx.x] += y;
        __syncthreads();
    }
    if (i < ntot) rowptr[i] = lds[threadIdx.x] - v;
    if (threadIdx.x == 1023) bsum[blockIdx.x] = lds[1023];
}

__global__ __launch_bounds__(1024) void scan2_kernel(int* __restrict__ bsum, int B) {
    __shared__ int lds[1024];
    int v = (threadIdx.x < B) ? bsum[threadIdx.x] : 0;
    lds[threadIdx.x] = v;
    __syncthreads();
    for (int off = 1; off < 1024; off <<= 1) {
        int y = (threadIdx.x >= off) ? lds[threadIdx.x - off] : 0;
        __syncthreads();
        if (threadIdx.x >= off) lds[threadIdx.x] += y;
        __syncthreads();
    }
    if (threadIdx.x < B) bsum[threadIdx.x] = lds[threadIdx.x] - v;
}

__global__ __launch_bounds__(256) void scan3_kernel(int* __restrict__ rowptr,
                                                    const int* __restrict__ bsum, int ntot) {
    int i = blockIdx.x * 256 + threadIdx.x;
    if (i < ntot) rowptr[i] += bsum[i >> 10];
}

// agg over 8 features; writes f32 aggx (c1 input) AND bf16 into Abf cols 128..135
// + zero tail cols 136..159.
__global__ __launch_bounds__(256) void agg8_kernel(const float* __restrict__ xs,
                                                   const int* __restrict__ rowptr,
                                                   const int* __restrict__ col,
                                                   const float* __restrict__ dinv,
                                                   float* __restrict__ aggx,
                                                   unsigned short* __restrict__ Abf,
                                                   int n) {
    int v = blockIdx.x * 256 + threadIdx.x;
    if (v >= n) return;
    const float4* r4 = (const float4*)xs;
    float4 a = make_float4(0, 0, 0, 0), b = make_float4(0, 0, 0, 0);
    int end = rowptr[v + 1];
    for (int j = rowptr[v]; j < end; j++) {
        int s = col[j];
        float4 p = r4[(size_t)s * 2], q = r4[(size_t)s * 2 + 1];
        a.x += p.x; a.y += p.y; a.z += p.z; a.w += p.w;
        b.x += q.x; b.y += q.y; b.z += q.z; b.w += q.w;
    }
    float4 p = r4[(size_t)v * 2], q = r4[(size_t)v * 2 + 1];
    a.x += p.x; a.y += p.y; a.z += p.z; a.w += p.w;
    b.x += q.x; b.y += q.y; b.z += q.z; b.w += q.w;
    float dv = dinv[v];
    a = make_float4(a.x * dv, a.y * dv, a.z * dv, a.w * dv);
    b = make_float4(b.x * dv, b.y * dv, b.z * dv, b.w * dv);
    float4* o = (float4*)aggx;
    o[(size_t)v * 2]     = a;
    o[(size_t)v * 2 + 1] = b;
    unsigned short u[8] = {f32_to_bf16_rne(a.x), f32_to_bf16_rne(a.y),
                           f32_to_bf16_rne(a.z), f32_to_bf16_rne(a.w),
                           f32_to_bf16_rne(b.x), f32_to_bf16_rne(b.y),
                           f32_to_bf16_rne(b.z), f32_to_bf16_rne(b.w)};
    ulonglong2 pk;
    pk.x = (unsigned long long)u[0] | ((unsigned long long)u[1] << 16)
         | ((unsigned long long)u[2] << 32) | ((unsigned long long)u[3] << 48);
    pk.y = (unsigned long long)u[4] | ((unsigned long long)u[5] << 16)
         | ((unsigned long long)u[6] << 32) | ((unsigned long long)u[7] << 48);
    *(ulonglong2*)&Abf[(size_t)v * 160 + 128] = pk;
    ulonglong2 z; z.x = 0ull; z.y = 0ull;
    *(ulonglong2*)&Abf[(size_t)v * 160 + 136] = z;
    *(ulonglong2*)&Abf[(size_t)v * 160 + 144] = z;
    *(ulonglong2*)&Abf[(size_t)v * 160 + 152] = z;
}

// agg over 128 bf16 features: one wave per node; writes bf16 into Abf cols 0..127
__global__ __launch_bounds__(256) void agg128_kernel(const unsigned* __restrict__ rows,
                                                     const int* __restrict__ rowptr,
                                                     const int* __restrict__ col,
                                                     const float* __restrict__ dinv,
                                                     unsigned short* __restrict__ Abf,
                                                     int n) {
    int v = blockIdx.x * 4 + (threadIdx.x >> 6);
    int lane = threadIdx.x & 63;
    if (v >= n) return;
    float ax = 0.f, ay = 0.f;
    int start = rowptr[v], end = rowptr[v + 1];
    for (int base = start; base < end; base += 64) {
        int m = end - base; if (m > 64) m = 64;
        int si = (lane < m) ? col[base + lane] : 0;
        int t = 0;
        for (; t + 4 <= m; t += 4) {
            int s0 = __shfl(si, t),     s1 = __shfl(si, t + 1);
            int s2 = __shfl(si, t + 2), s3 = __shfl(si, t + 3);
            unsigned u0 = rows[(size_t)s0 * 64 + lane];
            unsigned u1 = rows[(size_t)s1 * 64 + lane];
            unsigned u2 = rows[(size_t)s2 * 64 + lane];
            unsigned u3 = rows[(size_t)s3 * 64 + lane];
            ax += (__uint_as_float(u0 << 16) + __uint_as_float(u1 << 16))
                + (__uint_as_float(u2 << 16) + __uint_as_float(u3 << 16));
            ay += (__uint_as_float(u0 & 0xffff0000u) + __uint_as_float(u1 & 0xffff0000u))
                + (__uint_as_float(u2 & 0xffff0000u) + __uint_as_float(u3 & 0xffff0000u));
        }
        for (; t < m; t++) {
            int s = __shfl(si, t);
            unsigned u = rows[(size_t)s * 64 + lane];
            ax += __uint_as_float(u << 16);
            ay += __uint_as_float(u & 0xffff0000u);
        }
    }
    unsigned us = rows[(size_t)v * 64 + lane];
    ax += __uint_as_float(us << 16);
    ay += __uint_as_float(us & 0xffff0000u);
    float dv = dinv[v];
    unsigned pk = (unsigned)f32_to_bf16_rne(ax * dv)
                | ((unsigned)f32_to_bf16_rne(ay * dv) << 16);
    ((unsigned*)Abf)[(size_t)v * 80 + lane] = pk;
}

// c1 layer (K=8), fp32 VALU: h1s = bf16(relu(aggx @ c1W + c1b) * dinv)
__global__ __launch_bounds__(256) void gemm8_kernel(
    const float* __restrict__ A1, const float* __restrict__ W,
    const float* __restrict__ bias, const float* __restrict__ dinv,
    unsigned short* __restrict__ out, int n) {
    constexpr int K = 8, KP = 12, NPB = 32;
    __shared__ float lds[NPB * KP];
    int node0 = blockIdx.x * NPB;
    for (int idx = threadIdx.x; idx < NPB * K; idx += 256) {
        int r = idx / K, k = idx - r * K;
        int node = node0 + r;
        lds[r * KP + k] = (node < n) ? A1[(size_t)node * K + k] : 0.f;
    }
    __syncthreads();
    int f8 = threadIdx.x & 15, ng = threadIdx.x >> 4;
    int fbase = f8 * 8;
    float acc[2][8];
#pragma unroll
    for (int r = 0; r < 2; r++)
#pragma unroll
        for (int j = 0; j < 8; j++) acc[r][j] = 0.f;
    for (int k = 0; k < K; k += 4) {
        float4 wlo[4], whi[4];
#pragma unroll
        for (int kk = 0; kk < 4; kk++) {
            wlo[kk] = *(const float4*)&W[(size_t)(k + kk) * 128 + fbase];
            whi[kk] = *(const float4*)&W[(size_t)(k + kk) * 128 + fbase + 4];
        }
#pragma unroll
        for (int r = 0; r < 2; r++) {
            float4 a = *(const float4*)&lds[(2 * ng + r) * KP + k];
            float av[4] = {a.x, a.y, a.z, a.w};
#pragma unroll
            for (int kk = 0; kk < 4; kk++) {
                acc[r][0] += av[kk] * wlo[kk].x; acc[r][1] += av[kk] * wlo[kk].y;
                acc[r][2] += av[kk] * wlo[kk].z; acc[r][3] += av[kk] * wlo[kk].w;
                acc[r][4] += av[kk] * whi[kk].x; acc[r][5] += av[kk] * whi[kk].y;
                acc[r][6] += av[kk] * whi[kk].z; acc[r][7] += av[kk] * whi[kk].w;
            }
        }
    }
    float4 blo = *(const float4*)&bias[fbase];
    float4 bhi = *(const float4*)&bias[fbase + 4];
    float bv[8] = {blo.x, blo.y, blo.z, blo.w, bhi.x, bhi.y, bhi.z, bhi.w};
#pragma unroll
    for (int r = 0; r < 2; r++) {
        int node = node0 + 2 * ng + r;
        if (node < n) {
            float dv = dinv[node];
            unsigned short u[8];
#pragma unroll
            for (int j = 0; j < 8; j++)
                u[j] = f32_to_bf16_rne(fmaxf(acc[r][j] + bv[j], 0.f) * dv);
            ulonglong2 pk;
            pk.x = (unsigned long long)u[0] | ((unsigned long long)u[1] << 16)
                 | ((unsigned long long)u[2] << 32) | ((unsigned long long)u[3] << 48);
            pk.y = (unsigned long long)u[4] | ((unsigned long long)u[5] << 16)
                 | ((unsigned long long)u[6] << 32) | ((unsigned long long)u[7] << 48);
            *(ulonglong2*)&out[(size_t)node * 128 + fbase] = pk;
        }
    }
}

// Pack W[K x 128] f32 (K<=136) into MFMA B-fragment layout, K padded to 160
__global__ __launch_bounds__(256) void pack_w_kernel(const float* __restrict__ W,
                                                     unsigned short* __restrict__ wp, int K) {
    int t = blockIdx.x * 256 + threadIdx.x;
    if (t >= 20480) return;
    int i = t & 7, l = (t >> 3) & 63, fc = (t >> 9) & 7, ks = t >> 12;
    int k = ks * 32 + (l >> 4) * 8 + i;
    int c = (l & 15) + 16 * fc;
    float v = (k < K) ? W[(size_t)k * 128 + c] : 0.f;
    wp[t] = f32_to_bf16_rne(v);
}

// MFMA GEMM: C[N x 128] = A[N x 160 bf16] @ Wpack (+bias, relu)
// MODE 1: store bf16 h2 into Abf2 cols 8..135 (row stride 160)
// MODE 2: fused f5: out[row] = sigmoid(x[row]·f5W[0:8] + h4·f5W[8:136] + f5b)
template <int MODE>
__global__ __launch_bounds__(256) void mfma_gemm(
    const unsigned short* __restrict__ A, const unsigned short* __restrict__ wp,
    const float* __restrict__ bias, const float* __restrict__ x,
    const float* __restrict__ f5W, const float* __restrict__ f5b,
    void* __restrict__ outv, int n) {
    __shared__ float ldsx[64];
    int node0 = blockIdx.x * 64;
    if constexpr (MODE == 2) {
        if (threadIdx.x < 64) {
            int rc = min(node0 + (int)threadIdx.x, n - 1);
            float s = 0.f;
#pragma unroll
            for (int k = 0; k < 8; k++) s += x[(size_t)rc * 8 + k] * f5W[k];
            ldsx[threadIdx.x] = s;
        }
        __syncthreads();
    }
    int wave = threadIdx.x >> 6, lane = threadIdx.x & 63;
    int g = lane >> 4, r = lane & 15;
    int row0 = node0 + wave * 16;
    int arow = min(row0 + r, n - 1);

    short8 a[5];
#pragma unroll
    for (int ks = 0; ks < 5; ks++)
        a[ks] = *(const short8*)&A[(size_t)arow * 160 + ks * 32 + g * 8];

    f32x4 acc[8] = {};
#pragma unroll
    for (int ks = 0; ks < 5; ks++) {
#pragma unroll
        for (int fc = 0; fc < 8; fc++) {
            short8 w = *(const short8*)&wp[(size_t)((ks * 8 + fc) * 64 + lane) * 8];
            acc[fc] = __builtin_amdgcn_mfma_f32_16x16x32_bf16(a[ks], w, acc[fc], 0, 0, 0);
        }
    }

    if constexpr (MODE == 1) {
        unsigned short* out = (unsigned short*)outv;
#pragma unroll
        for (int fc = 0; fc < 8; fc++) {
            int c = r + 16 * fc;
            float bc = bias[c];
#pragma unroll
            for (int v = 0; v < 4; v++) {
                int row = row0 + 4 * g + v;
                if (row < n)
                    out[(size_t)row * 160 + 8 + c] =
                        f32_to_bf16_rne(fmaxf(acc[fc][v] + bc, 0.f));
            }
        }
    } else {
        float plog[4] = {0.f, 0.f, 0.f, 0.f};
#pragma unroll
        for (int fc = 0; fc < 8; fc++) {
            int c = r + 16 * fc;
            float bc = bias[c];
            float w5 = f5W[8 + c];
#pragma unroll
            for (int v = 0; v < 4; v++)
                plog[v] += fmaxf(acc[fc][v] + bc, 0.f) * w5;
        }
#pragma unroll
        for (int m = 1; m < 16; m <<= 1) {
#pragma unroll
            for (int v = 0; v < 4; v++) plog[v] += __shfl_xor(plog[v], m);
        }
        if (r == 0) {
            float* out = (float*)outv;
            float fb = f5b[0];
#pragma unroll
            for (int v = 0; v < 4; v++) {
                int row = row0 + 4 * g + v;
                if (row < n)
                    out[row] = 1.f / (1.f + expf(-(plog[v] + ldsx[wave * 16 + 4 * g + v] + fb)));
            }
        }
    }
}

extern "C" void kernel_launch(void* const* d_in, const int* in_sizes, int n_in,
                              void* d_out, int out_size, void* d_ws, size_t ws_size,
                              hipStream_t stream) {
    const float* x   = (const float*)d_in[0];
    const int*   ei  = (const int*)d_in[1];
    const float* c1W = (const float*)d_in[2];
    const float* c1b = (const float*)d_in[3];
    const float* c2W = (const float*)d_in[4];
    const float* c2b = (const float*)d_in[5];
    const float* f4W = (const float*)d_in[18];
    const float* f4b = (const float*)d_in[19];
    const float* f5W = (const float*)d_in[20];
    const float* f5b = (const float*)d_in[21];
    float* out = (float*)d_out;

    int N = in_sizes[0] / 8;
    int E = in_sizes[1] / 2;

    char* p = (char*)d_ws;
    auto alloc = [&](size_t bytes) {
        char* q = p;
        p += (bytes + 255) & ~(size_t)255;
        return q;
    };
    int*            cnt    = (int*)alloc((size_t)N * 4);
    int*            rowptr = (int*)alloc((size_t)(N + 1) * 4);
    int*            cursor = (int*)alloc((size_t)N * 4);
    int*            bsum   = (int*)alloc(4096);
    int*            bcnt   = (int*)alloc(256);
    float*          dinv   = (float*)alloc((size_t)N * 4);
    int*            col    = (int*)alloc((size_t)E * 4);
    float*          xs     = (float*)alloc((size_t)N * 8 * 4);
    float*          aggx   = (float*)alloc((size_t)N * 8 * 4);
    unsigned short* bufH1  = (unsigned short*)alloc((size_t)N * 128 * 2); // h1s bf16
    unsigned short* Abf    = (unsigned short*)alloc((size_t)N * 160 * 2); // [aggh1|aggx|0]
    unsigned short* Abf2   = (unsigned short*)alloc((size_t)N * 160 * 2); // [x|h2|0]
    unsigned short* wp2    = (unsigned short*)alloc(20480 * 2);
    unsigned short* wp4    = (unsigned short*)alloc(20480 * 2);

    // bucket aliases bufH1: consumed by hist2/fill2 before gemm8 writes bufH1
    const int cap = 300000;                       // 8*cap*8B = 19.2MB <= 25.6MB
    int2* bucket = (int2*)bufH1;

    (void)hipMemsetAsync(cnt, 0, (size_t)N * 4, stream);
    (void)hipMemsetAsync(bcnt, 0, 32, stream);

    int gN = (N + 255) / 256;
    pack_w_kernel<<<80, 256, 0, stream>>>(c2W, wp2, 136);
    pack_w_kernel<<<80, 256, 0, stream>>>(f4W, wp4, 136);

    // Phase 1: bucket (single ei pass, ballot-packed, no atomics on cnt)
    int gB = (E + 1023) / 1024;
    bucket_kernel<<<gB, 256, 0, stream>>>(ei, bcnt, bucket, E, N, cap);

    // Phase 1b: per-XCD histogram (cnt slice L2-local)
    int nchunk = 128;
    hist2_kernel<<<8 * nchunk, 256, 0, stream>>>(bucket, bcnt, cnt, cap, nchunk);

    dinv_xs_kernel<<<gN, 256, 0, stream>>>(cnt, x, dinv, xs, Abf2, N);

    int ntot = N + 1;
    int B = (ntot + 1023) / 1024;
    scan1_kernel<<<B, 1024, 0, stream>>>(cnt, rowptr, bsum, ntot, N);
    scan2_kernel<<<1, 1024, 0, stream>>>(bsum, B);
    scan3_kernel<<<(ntot + 255) / 256, 256, 0, stream>>>(rowptr, bsum, ntot);

    (void)hipMemcpyAsync(cursor, rowptr, (size_t)N * 4, hipMemcpyDeviceToDevice, stream);

    // Phase 2: per-XCD CSR fill from own bucket
    fill2_kernel<<<8 * nchunk, 256, 0, stream>>>(bucket, bcnt, cursor, col, cap, nchunk);

    agg8_kernel<<<gN, 256, 0, stream>>>(xs, rowptr, col, dinv, aggx, Abf, N);

    // h1s = bf16( relu(aggx @ c1W + c1b) * dinv )
    gemm8_kernel<<<(N + 31) / 32, 256, 0, stream>>>(aggx, c1W, c1b, dinv, bufH1, N);

    // aggh1 (bf16) into Abf cols 0..127
    agg128_kernel<<<(N + 3) / 4, 256, 0, stream>>>((const unsigned*)bufH1, rowptr, col,
                                                   dinv, Abf, N);

    int g64 = (N + 63) / 64;
    // h2 = relu([aggh1, aggx] @ c2W + c2b) -> bf16 into Abf2 cols 8..135
    mfma_gemm<1><<<g64, 256, 0, stream>>>(Abf, wp2, c2b, nullptr, nullptr, nullptr,
                                          Abf2, N);
    // h4 = relu([x, h2] @ f4W + f4b); out = sigmoid([x, h4] @ f5W + f5b)
    mfma_gemm<2><<<g64, 256, 0, stream>>>(Abf2, wp4, f4b, x, f5W, f5b, out, N);
}

// Round 9
// 328.182 us; speedup vs baseline: 1.0121x; 1.0121x over previous
//
#include <hip/hip_runtime.h>
#include <hip/hip_bf16.h>
#include <math.h>

// ---------------------------------------------------------------------------
// Live computation (dead-code-eliminated reference):
//   dinv[v] = rsqrt(indeg(v)+1)
//   aggx    = A_norm @ x
//   h1s     = relu(aggx @ c1W + c1b) * dinv       (bf16)
//   aggh1   = A_norm @ h1
//   h2      = relu([aggh1, aggx] @ c2W + c2b)     (MFMA bf16, K padded to 160)
//   h4      = relu([x, h2] @ f4W + f4b)           (MFMA bf16)
//   out     = sigmoid([x, h4] @ f5W + f5b)        (fused into f4 epilogue)
// CSR build with ZERO per-edge global atomics (they cost ~40B EA write each):
//   bucket (ballot-pack by XCD range) -> per-sub-range LDS histogram ->
//   global scan -> per-sub-range LDS-cursor fill.
// ---------------------------------------------------------------------------

typedef __attribute__((ext_vector_type(8))) short short8;
typedef __attribute__((ext_vector_type(4))) float f32x4;

__device__ __forceinline__ unsigned short f32_to_bf16_rne(float f) {
    unsigned u = __float_as_uint(f);
    return (unsigned short)((u + 0x7fffu + ((u >> 16) & 1u)) >> 16);
}

// Phase 1: stream ei once; append (s,d) to bucket[part(d)] via wave ballot
// ranking (no LDS atomics, no histogram).
__global__ __launch_bounds__(256) void bucket_kernel(
    const int* __restrict__ ei,
    int* __restrict__ bcnt, int2* __restrict__ bucket,
    int E, int N, int cap) {
    constexpr int EPB = 1024;          // 4 waves x 4 chunks x 64 lanes
    __shared__ int wcnt_s[4][8];
    __shared__ int wofs_s[4][8];
    __shared__ int lbase_s[8];

    int wave = threadIdx.x >> 6, lane = threadIdx.x & 63;
    unsigned long long ltmask = (lane == 63) ? 0x7fffffffffffffffull
                                             : ((1ull << lane) - 1ull);
    int ebase = blockIdx.x * EPB + wave * 256;

    int2 v[4];
    int  pv[4];
    int  wcnt[8];
#pragma unroll
    for (int P = 0; P < 8; P++) wcnt[P] = 0;

    // pass 1: load, classify, count (ballot)
#pragma unroll
    for (int c = 0; c < 4; c++) {
        int e = ebase + c * 64 + lane;
        pv[c] = 8;                                   // invalid sentinel
        if (e < E) {
            v[c] = ((const int2*)ei)[e];
            if ((unsigned)v[c].y < (unsigned)N) {
                pv[c] = (int)(((unsigned long long)(unsigned)v[c].y * 8ull)
                              / (unsigned)N);
                if ((unsigned)v[c].x >= (unsigned)N) v[c].x = 0;
            }
        }
#pragma unroll
        for (int P = 0; P < 8; P++)
            wcnt[P] += __popcll(__ballot(pv[c] == P));
    }

    if (lane == 0) {
#pragma unroll
        for (int P = 0; P < 8; P++) wcnt_s[wave][P] = wcnt[P];
    }
    __syncthreads();
    if (threadIdx.x < 8) {
        int P = threadIdx.x;
        int tot = 0;
#pragma unroll
        for (int w = 0; w < 4; w++) { wofs_s[w][P] = tot; tot += wcnt_s[w][P]; }
        lbase_s[P] = atomicAdd(&bcnt[P], tot);
    }
    __syncthreads();

    int woff[8];
#pragma unroll
    for (int P = 0; P < 8; P++) woff[P] = lbase_s[P] + wofs_s[wave][P];

    // pass 2: ballot-ranked scatter into buckets (contiguous per part/wave)
#pragma unroll
    for (int c = 0; c < 4; c++) {
#pragma unroll
        for (int P = 0; P < 8; P++) {
            unsigned long long m = __ballot(pv[c] == P);
            if (pv[c] == P) {
                int slot = woff[P] + __popcll(m & ltmask);
                if (slot < cap) bucket[(size_t)P * cap + slot] = v[c];
            }
            woff[P] += __popcll(m);
        }
    }
}

// Phase 1b: per-sub-range LDS histogram. Block (p = blockIdx&7, s = blockIdx>>3)
// owns node range [N*(32p+s)/256, N*(32p+s+1)/256) inside part p. Streams its
// part's bucket from L2 (32x reuse per XCD), counts in LDS, writes cnt
// NON-atomically (each node owned by exactly one block).
__global__ __launch_bounds__(1024) void count_kernel(
    const int2* __restrict__ bucket, const int* __restrict__ bcnt,
    int* __restrict__ cnt, int N, int cap) {
    __shared__ int lcnt[512];
    int p = blockIdx.x & 7;
    int s = blockIdx.x >> 3;
    int gidx = p * 32 + s;
    int lo = (int)((long long)N * gidx / 256);
    int hi = (int)((long long)N * (gidx + 1) / 256);
    int range = hi - lo;
    for (int i = threadIdx.x; i < range; i += 1024) lcnt[i] = 0;
    __syncthreads();
    int n = min(bcnt[p], cap);
    const int2* b = bucket + (size_t)p * cap;
    for (int i = threadIdx.x; i < n; i += 1024) {
        int d = b[i].y;
        if (d >= lo && d < hi) atomicAdd(&lcnt[d - lo], 1);
    }
    __syncthreads();
    for (int i = threadIdx.x; i < range; i += 1024) cnt[lo + i] = lcnt[i];
}

// Phase 2: per-sub-range fill with LDS cursors (zero global atomics).
// Block's col segment [rowptr[lo], rowptr[hi]) is contiguous -> full-line WB.
__global__ __launch_bounds__(1024) void fill3_kernel(
    const int2* __restrict__ bucket, const int* __restrict__ bcnt,
    const int* __restrict__ rowptr, int* __restrict__ col, int N, int cap) {
    __shared__ int cur[512];
    int p = blockIdx.x & 7;
    int s = blockIdx.x >> 3;
    int gidx = p * 32 + s;
    int lo = (int)((long long)N * gidx / 256);
    int hi = (int)((long long)N * (gidx + 1) / 256);
    int range = hi - lo;
    for (int i = threadIdx.x; i < range; i += 1024) cur[i] = rowptr[lo + i];
    __syncthreads();
    int n = min(bcnt[p], cap);
    const int2* b = bucket + (size_t)p * cap;
    for (int i = threadIdx.x; i < n; i += 1024) {
        int2 v = b[i];
        if (v.y >= lo && v.y < hi) {
            int pos = atomicAdd(&cur[v.y - lo], 1);
            col[pos] = v.x;
        }
    }
}

// dinv, xs (x*dinv f32), and Abf2 cols 0..7 = bf16(x) + zero tail cols 136..159
__global__ __launch_bounds__(256) void dinv_xs_kernel(const int* __restrict__ cnt,
                                                      const float* __restrict__ x,
                                                      float* __restrict__ dinv,
                                                      float* __restrict__ xs,
                                                      unsigned short* __restrict__ Abf2,
                                                      int n) {
    int v = blockIdx.x * 256 + threadIdx.x;
    if (v >= n) return;
    float dv = rsqrtf((float)(cnt[v] + 1));
    dinv[v] = dv;
    const float4* x4 = (const float4*)x;
    float4 a = x4[v * 2], b = x4[v * 2 + 1];
    float4* o = (float4*)xs;
    o[v * 2]     = make_float4(a.x * dv, a.y * dv, a.z * dv, a.w * dv);
    o[v * 2 + 1] = make_float4(b.x * dv, b.y * dv, b.z * dv, b.w * dv);
    unsigned short u[8] = {f32_to_bf16_rne(a.x), f32_to_bf16_rne(a.y),
                           f32_to_bf16_rne(a.z), f32_to_bf16_rne(a.w),
                           f32_to_bf16_rne(b.x), f32_to_bf16_rne(b.y),
                           f32_to_bf16_rne(b.z), f32_to_bf16_rne(b.w)};
    ulonglong2 pk;
    pk.x = (unsigned long long)u[0] | ((unsigned long long)u[1] << 16)
         | ((unsigned long long)u[2] << 32) | ((unsigned long long)u[3] << 48);
    pk.y = (unsigned long long)u[4] | ((unsigned long long)u[5] << 16)
         | ((unsigned long long)u[6] << 32) | ((unsigned long long)u[7] << 48);
    *(ulonglong2*)&Abf2[(size_t)v * 160] = pk;
    ulonglong2 z; z.x = 0ull; z.y = 0ull;
    *(ulonglong2*)&Abf2[(size_t)v * 160 + 136] = z;
    *(ulonglong2*)&Abf2[(size_t)v * 160 + 144] = z;
    *(ulonglong2*)&Abf2[(size_t)v * 160 + 152] = z;
}

// exclusive scan of cnt into rowptr
__global__ __launch_bounds__(1024) void scan1_kernel(const int* __restrict__ cnt,
                                                     int* __restrict__ rowptr,
                                                     int* __restrict__ bsum, int ntot, int N) {
    __shared__ int lds[1024];
    int i = blockIdx.x * 1024 + threadIdx.x;
    int v = (i < N) ? cnt[i] : 0;
    lds[threadIdx.x] = v;
    __syncthreads();
    for (int off = 1; off < 1024; off <<= 1) {
        int y = (threadIdx.x >= off) ? lds[threadIdx.x - off] : 0;
        __syncthreads();
        if (threadIdx.x >= off) lds[threadIdx.x] += y;
        __syncthreads();
    }
    if (i < ntot) rowptr[i] = lds[threadIdx.x] - v;
    if (threadIdx.x == 1023) bsum[blockIdx.x] = lds[1023];
}

__global__ __launch_bounds__(1024) void scan2_kernel(int* __restrict__ bsum, int B) {
    __shared__ int lds[1024];
    int v = (threadIdx.x < B) ? bsum[threadIdx.x] : 0;
    lds[threadIdx.x] = v;
    __syncthreads();
    for (int off = 1; off < 1024; off <<= 1) {
        int y = (threadIdx.x >= off) ? lds[threadIdx.x - off] : 0;
        __syncthreads();
        if (threadIdx.x >= off) lds[threadIdx.x] += y;
        __syncthreads();
    }
    if (threadIdx.x < B) bsum[threadIdx.x] = lds[threadIdx.x] - v;
}

__global__ __launch_bounds__(256) void scan3_kernel(int* __restrict__ rowptr,
                                                    const int* __restrict__ bsum, int ntot) {
    int i = blockIdx.x * 256 + threadIdx.x;
    if (i < ntot) rowptr[i] += bsum[i >> 10];
}

// agg over 8 features; writes f32 aggx (c1 input) AND bf16 into Abf cols 128..135
// + zero tail cols 136..159.
__global__ __launch_bounds__(256) void agg8_kernel(const float* __restrict__ xs,
                                                   const int* __restrict__ rowptr,
                                                   const int* __restrict__ col,
                                                   const float* __restrict__ dinv,
                                                   float* __restrict__ aggx,
                                                   unsigned short* __restrict__ Abf,
                                                   int n) {
    int v = blockIdx.x * 256 + threadIdx.x;
    if (v >= n) return;
    const float4* r4 = (const float4*)xs;
    float4 a = make_float4(0, 0, 0, 0), b = make_float4(0, 0, 0, 0);
    int end = rowptr[v + 1];
    for (int j = rowptr[v]; j < end; j++) {
        int s = col[j];
        float4 p = r4[(size_t)s * 2], q = r4[(size_t)s * 2 + 1];
        a.x += p.x; a.y += p.y; a.z += p.z; a.w += p.w;
        b.x += q.x; b.y += q.y; b.z += q.z; b.w += q.w;
    }
    float4 p = r4[(size_t)v * 2], q = r4[(size_t)v * 2 + 1];
    a.x += p.x; a.y += p.y; a.z += p.z; a.w += p.w;
    b.x += q.x; b.y += q.y; b.z += q.z; b.w += q.w;
    float dv = dinv[v];
    a = make_float4(a.x * dv, a.y * dv, a.z * dv, a.w * dv);
    b = make_float4(b.x * dv, b.y * dv, b.z * dv, b.w * dv);
    float4* o = (float4*)aggx;
    o[(size_t)v * 2]     = a;
    o[(size_t)v * 2 + 1] = b;
    unsigned short u[8] = {f32_to_bf16_rne(a.x), f32_to_bf16_rne(a.y),
                           f32_to_bf16_rne(a.z), f32_to_bf16_rne(a.w),
                           f32_to_bf16_rne(b.x), f32_to_bf16_rne(b.y),
                           f32_to_bf16_rne(b.z), f32_to_bf16_rne(b.w)};
    ulonglong2 pk;
    pk.x = (unsigned long long)u[0] | ((unsigned long long)u[1] << 16)
         | ((unsigned long long)u[2] << 32) | ((unsigned long long)u[3] << 48);
    pk.y = (unsigned long long)u[4] | ((unsigned long long)u[5] << 16)
         | ((unsigned long long)u[6] << 32) | ((unsigned long long)u[7] << 48);
    *(ulonglong2*)&Abf[(size_t)v * 160 + 128] = pk;
    ulonglong2 z; z.x = 0ull; z.y = 0ull;
    *(ulonglong2*)&Abf[(size_t)v * 160 + 136] = z;
    *(ulonglong2*)&Abf[(size_t)v * 160 + 144] = z;
    *(ulonglong2*)&Abf[(size_t)v * 160 + 152] = z;
}

// agg over 128 bf16 features: one wave per node; writes bf16 into Abf cols 0..127
__global__ __launch_bounds__(256) void agg128_kernel(const unsigned* __restrict__ rows,
                                                     const int* __restrict__ rowptr,
                                                     const int* __restrict__ col,
                                                     const float* __restrict__ dinv,
                                                     unsigned short* __restrict__ Abf,
                                                     int n) {
    int v = blockIdx.x * 4 + (threadIdx.x >> 6);
    int lane = threadIdx.x & 63;
    if (v >= n) return;
    float ax = 0.f, ay = 0.f;
    int start = rowptr[v], end = rowptr[v + 1];
    for (int base = start; base < end; base += 64) {
        int m = end - base; if (m > 64) m = 64;
        int si = (lane < m) ? col[base + lane] : 0;
        int t = 0;
        for (; t + 4 <= m; t += 4) {
            int s0 = __shfl(si, t),     s1 = __shfl(si, t + 1);
            int s2 = __shfl(si, t + 2), s3 = __shfl(si, t + 3);
            unsigned u0 = rows[(size_t)s0 * 64 + lane];
            unsigned u1 = rows[(size_t)s1 * 64 + lane];
            unsigned u2 = rows[(size_t)s2 * 64 + lane];
            unsigned u3 = rows[(size_t)s3 * 64 + lane];
            ax += (__uint_as_float(u0 << 16) + __uint_as_float(u1 << 16))
                + (__uint_as_float(u2 << 16) + __uint_as_float(u3 << 16));
            ay += (__uint_as_float(u0 & 0xffff0000u) + __uint_as_float(u1 & 0xffff0000u))
                + (__uint_as_float(u2 & 0xffff0000u) + __uint_as_float(u3 & 0xffff0000u));
        }
        for (; t < m; t++) {
            int s = __shfl(si, t);
            unsigned u = rows[(size_t)s * 64 + lane];
            ax += __uint_as_float(u << 16);
            ay += __uint_as_float(u & 0xffff0000u);
        }
    }
    unsigned us = rows[(size_t)v * 64 + lane];
    ax += __uint_as_float(us << 16);
    ay += __uint_as_float(us & 0xffff0000u);
    float dv = dinv[v];
    unsigned pk = (unsigned)f32_to_bf16_rne(ax * dv)
                | ((unsigned)f32_to_bf16_rne(ay * dv) << 16);
    ((unsigned*)Abf)[(size_t)v * 80 + lane] = pk;
}

// c1 layer (K=8), fp32 VALU: h1s = bf16(relu(aggx @ c1W + c1b) * dinv)
__global__ __launch_bounds__(256) void gemm8_kernel(
    const float* __restrict__ A1, const float* __restrict__ W,
    const float* __restrict__ bias, const float* __restrict__ dinv,
    unsigned short* __restrict__ out, int n) {
    constexpr int K = 8, KP = 12, NPB = 32;
    __shared__ float lds[NPB * KP];
    int node0 = blockIdx.x * NPB;
    for (int idx = threadIdx.x; idx < NPB * K; idx += 256) {
        int r = idx / K, k = idx - r * K;
        int node = node0 + r;
        lds[r * KP + k] = (node < n) ? A1[(size_t)node * K + k] : 0.f;
    }
    __syncthreads();
    int f8 = threadIdx.x & 15, ng = threadIdx.x >> 4;
    int fbase = f8 * 8;
    float acc[2][8];
#pragma unroll
    for (int r = 0; r < 2; r++)
#pragma unroll
        for (int j = 0; j < 8; j++) acc[r][j] = 0.f;
    for (int k = 0; k < K; k += 4) {
        float4 wlo[4], whi[4];
#pragma unroll
        for (int kk = 0; kk < 4; kk++) {
            wlo[kk] = *(const float4*)&W[(size_t)(k + kk) * 128 + fbase];
            whi[kk] = *(const float4*)&W[(size_t)(k + kk) * 128 + fbase + 4];
        }
#pragma unroll
        for (int r = 0; r < 2; r++) {
            float4 a = *(const float4*)&lds[(2 * ng + r) * KP + k];
            float av[4] = {a.x, a.y, a.z, a.w};
#pragma unroll
            for (int kk = 0; kk < 4; kk++) {
                acc[r][0] += av[kk] * wlo[kk].x; acc[r][1] += av[kk] * wlo[kk].y;
                acc[r][2] += av[kk] * wlo[kk].z; acc[r][3] += av[kk] * wlo[kk].w;
                acc[r][4] += av[kk] * whi[kk].x; acc[r][5] += av[kk] * whi[kk].y;
                acc[r][6] += av[kk] * whi[kk].z; acc[r][7] += av[kk] * whi[kk].w;
            }
        }
    }
    float4 blo = *(const float4*)&bias[fbase];
    float4 bhi = *(const float4*)&bias[fbase + 4];
    float bv[8] = {blo.x, blo.y, blo.z, blo.w, bhi.x, bhi.y, bhi.z, bhi.w};
#pragma unroll
    for (int r = 0; r < 2; r++) {
        int node = node0 + 2 * ng + r;
        if (node < n) {
            float dv = dinv[node];
            unsigned short u[8];
#pragma unroll
            for (int j = 0; j < 8; j++)
                u[j] = f32_to_bf16_rne(fmaxf(acc[r][j] + bv[j], 0.f) * dv);
            ulonglong2 pk;
            pk.x = (unsigned long long)u[0] | ((unsigned long long)u[1] << 16)
                 | ((unsigned long long)u[2] << 32) | ((unsigned long long)u[3] << 48);
            pk.y = (unsigned long long)u[4] | ((unsigned long long)u[5] << 16)
                 | ((unsigned long long)u[6] << 32) | ((unsigned long long)u[7] << 48);
            *(ulonglong2*)&out[(size_t)node * 128 + fbase] = pk;
        }
    }
}

// Pack W[K x 128] f32 (K<=136) into MFMA B-fragment layout, K padded to 160
__global__ __launch_bounds__(256) void pack_w_kernel(const float* __restrict__ W,
                                                     unsigned short* __restrict__ wp, int K) {
    int t = blockIdx.x * 256 + threadIdx.x;
    if (t >= 20480) return;
    int i = t & 7, l = (t >> 3) & 63, fc = (t >> 9) & 7, ks = t >> 12;
    int k = ks * 32 + (l >> 4) * 8 + i;
    int c = (l & 15) + 16 * fc;
    float v = (k < K) ? W[(size_t)k * 128 + c] : 0.f;
    wp[t] = f32_to_bf16_rne(v);
}

// MFMA GEMM: C[N x 128] = A[N x 160 bf16] @ Wpack (+bias, relu)
// MODE 1: store bf16 h2 into Abf2 cols 8..135 (row stride 160)
// MODE 2: fused f5: out[row] = sigmoid(x[row]·f5W[0:8] + h4·f5W[8:136] + f5b)
template <int MODE>
__global__ __launch_bounds__(256) void mfma_gemm(
    const unsigned short* __restrict__ A, const unsigned short* __restrict__ wp,
    const float* __restrict__ bias, const float* __restrict__ x,
    const float* __restrict__ f5W, const float* __restrict__ f5b,
    void* __restrict__ outv, int n) {
    __shared__ float ldsx[64];
    int node0 = blockIdx.x * 64;
    if constexpr (MODE == 2) {
        if (threadIdx.x < 64) {
            int rc = min(node0 + (int)threadIdx.x, n - 1);
            float s = 0.f;
#pragma unroll
            for (int k = 0; k < 8; k++) s += x[(size_t)rc * 8 + k] * f5W[k];
            ldsx[threadIdx.x] = s;
        }
        __syncthreads();
    }
    int wave = threadIdx.x >> 6, lane = threadIdx.x & 63;
    int g = lane >> 4, r = lane & 15;
    int row0 = node0 + wave * 16;
    int arow = min(row0 + r, n - 1);

    short8 a[5];
#pragma unroll
    for (int ks = 0; ks < 5; ks++)
        a[ks] = *(const short8*)&A[(size_t)arow * 160 + ks * 32 + g * 8];

    f32x4 acc[8] = {};
#pragma unroll
    for (int ks = 0; ks < 5; ks++) {
#pragma unroll
        for (int fc = 0; fc < 8; fc++) {
            short8 w = *(const short8*)&wp[(size_t)((ks * 8 + fc) * 64 + lane) * 8];
            acc[fc] = __builtin_amdgcn_mfma_f32_16x16x32_bf16(a[ks], w, acc[fc], 0, 0, 0);
        }
    }

    if constexpr (MODE == 1) {
        unsigned short* out = (unsigned short*)outv;
#pragma unroll
        for (int fc = 0; fc < 8; fc++) {
            int c = r + 16 * fc;
            float bc = bias[c];
#pragma unroll
            for (int v = 0; v < 4; v++) {
                int row = row0 + 4 * g + v;
                if (row < n)
                    out[(size_t)row * 160 + 8 + c] =
                        f32_to_bf16_rne(fmaxf(acc[fc][v] + bc, 0.f));
            }
        }
    } else {
        float plog[4] = {0.f, 0.f, 0.f, 0.f};
#pragma unroll
        for (int fc = 0; fc < 8; fc++) {
            int c = r + 16 * fc;
            float bc = bias[c];
            float w5 = f5W[8 + c];
#pragma unroll
            for (int v = 0; v < 4; v++)
                plog[v] += fmaxf(acc[fc][v] + bc, 0.f) * w5;
        }
#pragma unroll
        for (int m = 1; m < 16; m <<= 1) {
#pragma unroll
            for (int v = 0; v < 4; v++) plog[v] += __shfl_xor(plog[v], m);
        }
        if (r == 0) {
            float* out = (float*)outv;
            float fb = f5b[0];
#pragma unroll
            for (int v = 0; v < 4; v++) {
                int row = row0 + 4 * g + v;
                if (row < n)
                    out[row] = 1.f / (1.f + expf(-(plog[v] + ldsx[wave * 16 + 4 * g + v] + fb)));
            }
        }
    }
}

extern "C" void kernel_launch(void* const* d_in, const int* in_sizes, int n_in,
                              void* d_out, int out_size, void* d_ws, size_t ws_size,
                              hipStream_t stream) {
    const float* x   = (const float*)d_in[0];
    const int*   ei  = (const int*)d_in[1];
    const float* c1W = (const float*)d_in[2];
    const float* c1b = (const float*)d_in[3];
    const float* c2W = (const float*)d_in[4];
    const float* c2b = (const float*)d_in[5];
    const float* f4W = (const float*)d_in[18];
    const float* f4b = (const float*)d_in[19];
    const float* f5W = (const float*)d_in[20];
    const float* f5b = (const float*)d_in[21];
    float* out = (float*)d_out;

    int N = in_sizes[0] / 8;
    int E = in_sizes[1] / 2;

    char* p = (char*)d_ws;
    auto alloc = [&](size_t bytes) {
        char* q = p;
        p += (bytes + 255) & ~(size_t)255;
        return q;
    };
    int*            cnt    = (int*)alloc((size_t)N * 4);
    int*            rowptr = (int*)alloc((size_t)(N + 1) * 4);
    int*            bsum   = (int*)alloc(4096);
    int*            bcnt   = (int*)alloc(256);
    float*          dinv   = (float*)alloc((size_t)N * 4);
    int*            col    = (int*)alloc((size_t)E * 4);
    float*          xs     = (float*)alloc((size_t)N * 8 * 4);
    float*          aggx   = (float*)alloc((size_t)N * 8 * 4);
    unsigned short* bufH1  = (unsigned short*)alloc((size_t)N * 128 * 2); // h1s bf16
    unsigned short* Abf    = (unsigned short*)alloc((size_t)N * 160 * 2); // [aggh1|aggx|0]
    unsigned short* Abf2   = (unsigned short*)alloc((size_t)N * 160 * 2); // [x|h2|0]
    unsigned short* wp2    = (unsigned short*)alloc(20480 * 2);
    unsigned short* wp4    = (unsigned short*)alloc(20480 * 2);

    // bucket aliases bufH1: consumed by count/fill3 before gemm8 writes bufH1
    const int cap = 300000;                       // 8*cap*8B = 19.2MB <= 25.6MB
    int2* bucket = (int2*)bufH1;

    (void)hipMemsetAsync(bcnt, 0, 32, stream);

    int gN = (N + 255) / 256;
    pack_w_kernel<<<80, 256, 0, stream>>>(c2W, wp2, 136);
    pack_w_kernel<<<80, 256, 0, stream>>>(f4W, wp4, 136);

    // Phase 1: bucket (single ei pass, ballot-packed, zero cnt atomics)
    int gB = (E + 1023) / 1024;
    bucket_kernel<<<gB, 256, 0, stream>>>(ei, bcnt, bucket, E, N, cap);

    // Phase 1b: per-sub-range LDS histogram (no global atomics, no memset)
    count_kernel<<<256, 1024, 0, stream>>>(bucket, bcnt, cnt, N, cap);

    dinv_xs_kernel<<<gN, 256, 0, stream>>>(cnt, x, dinv, xs, Abf2, N);

    int ntot = N + 1;
    int B = (ntot + 1023) / 1024;
    scan1_kernel<<<B, 1024, 0, stream>>>(cnt, rowptr, bsum, ntot, N);
    scan2_kernel<<<1, 1024, 0, stream>>>(bsum, B);
    scan3_kernel<<<(ntot + 255) / 256, 256, 0, stream>>>(rowptr, bsum, ntot);

    // Phase 2: per-sub-range CSR fill with LDS cursors (no global atomics)
    fill3_kernel<<<256, 1024, 0, stream>>>(bucket, bcnt, rowptr, col, N, cap);

    agg8_kernel<<<gN, 256, 0, stream>>>(xs, rowptr, col, dinv, aggx, Abf, N);

    // h1s = bf16( relu(aggx @ c1W + c1b) * dinv )
    gemm8_kernel<<<(N + 31) / 32, 256, 0, stream>>>(aggx, c1W, c1b, dinv, bufH1, N);

    // aggh1 (bf16) into Abf cols 0..127
    agg128_kernel<<<(N + 3) / 4, 256, 0, stream>>>((const unsigned*)bufH1, rowptr, col,
                                                   dinv, Abf, N);

    int g64 = (N + 63) / 64;
    // h2 = relu([aggh1, aggx] @ c2W + c2b) -> bf16 into Abf2 cols 8..135
    mfma_gemm<1><<<g64, 256, 0, stream>>>(Abf, wp2, c2b, nullptr, nullptr, nullptr,
                                          Abf2, N);
    // h4 = relu([x, h2] @ f4W + f4b); out = sigmoid([x, h4] @ f5W + f5b)
    mfma_gemm<2><<<g64, 256, 0, stream>>>(Abf2, wp4, f4b, x, f5W, f5b, out, N);
}

// Round 11
// 205.293 us; speedup vs baseline: 1.6179x; 1.5986x over previous
//
#include <hip/hip_runtime.h>
#include <hip/hip_bf16.h>
#include <math.h>

// ---------------------------------------------------------------------------
// Live computation (dead-code-eliminated reference):
//   dinv[v] = rsqrt(indeg(v)+1)
//   aggx    = A_norm @ x
//   h1s     = relu(aggx @ c1W + c1b) * dinv       (bf16)
//   aggh1   = A_norm @ h1
//   h2      = relu([aggh1, aggx] @ c2W + c2b)     (MFMA bf16, K padded to 160)
//   h4      = relu([x, h2] @ f4W + f4b)           (MFMA bf16)
//   out     = sigmoid([x, h4] @ f5W + f5b)        (fused into f4 epilogue)
// CSR build, v3: 128-way bucket (LDS-atomic ranking) -> fused per-bucket
// csr kernel (LDS hist + LDS scan + LDS-cursor fill). Bucket b's node range
// is the EXACT preimage of b = floor(y*128/N): [ceil(bN/128), ceil((b+1)N/128)).
// ---------------------------------------------------------------------------

#define NBUK 128

typedef __attribute__((ext_vector_type(8))) short short8;
typedef __attribute__((ext_vector_type(4))) float f32x4;

__device__ __forceinline__ unsigned short f32_to_bf16_rne(float f) {
    unsigned u = __float_as_uint(f);
    return (unsigned short)((u + 0x7fffu + ((u >> 16) & 1u)) >> 16);
}

// Phase 1: stream ei once; classify d into 128 ranges; LDS-atomic rank;
// append (s,d) to bucket[b]. bcnt_pad is line-padded (stride 16 ints).
__global__ __launch_bounds__(512) void bucket_kernel(
    const int* __restrict__ ei, int* __restrict__ bcnt_pad,
    int2* __restrict__ bucket, int E, int N, int cap) {
    constexpr int EPB = 8192;
    __shared__ int lcnt[NBUK];
    __shared__ int lcur[NBUK];
    int e0 = blockIdx.x * EPB;
    int e1 = min(e0 + EPB, E);
    if (threadIdx.x < NBUK) lcnt[threadIdx.x] = 0;
    __syncthreads();
    // pass A: count per bucket (LDS atomics, 128 counters -> ~2-way max)
    for (int e = e0 + threadIdx.x; e < e1; e += 512) {
        int2 v = ((const int2*)ei)[e];
        if ((unsigned)v.y < (unsigned)N) {
            int b = (int)(((unsigned long long)(unsigned)v.y * NBUK) / (unsigned)N);
            atomicAdd(&lcnt[b], 1);
        }
    }
    __syncthreads();
    if (threadIdx.x < NBUK)
        lcur[threadIdx.x] = atomicAdd(&bcnt_pad[threadIdx.x * 16], lcnt[threadIdx.x]);
    __syncthreads();
    // pass B: re-stream (L2-hot), LDS-cursor rank, scatter to bucket
    for (int e = e0 + threadIdx.x; e < e1; e += 512) {
        int2 v = ((const int2*)ei)[e];
        if ((unsigned)v.y < (unsigned)N) {
            int b = (int)(((unsigned long long)(unsigned)v.y * NBUK) / (unsigned)N);
            int pos = atomicAdd(&lcur[b], 1);
            if (pos < cap) {
                int s = ((unsigned)v.x < (unsigned)N) ? v.x : 0;
                bucket[(size_t)b * cap + pos] = make_int2(s, v.y);
            }
        }
    }
}

// Phase 2 (fused count+scan+fill): block b streams ONLY bucket b (~100KB).
// Node range = exact preimage of the classifier: [ceil(bN/128), ceil((b+1)N/128)).
__global__ __launch_bounds__(1024) void csr_kernel(
    const int2* __restrict__ bucket, const int* __restrict__ bcnt_pad,
    int* __restrict__ cnt, int* __restrict__ rowstart, int* __restrict__ col,
    int N, int cap) {
    __shared__ int lcnt[1024];
    __shared__ int lscan[1024];
    int b = blockIdx.x;
    int lo = (int)(((long long)b * N + NBUK - 1) / NBUK);        // ceil
    int hi = (int)(((long long)(b + 1) * N + NBUK - 1) / NBUK);  // ceil
    int range = hi - lo;
    lcnt[threadIdx.x] = 0;
    __syncthreads();
    int n = min(bcnt_pad[b * 16], cap);
    const int2* bk = bucket + (size_t)b * cap;
    for (int i = threadIdx.x; i < n; i += 1024)
        atomicAdd(&lcnt[bk[i].y - lo], 1);
    __syncthreads();
    int myc = lcnt[threadIdx.x];
    if ((int)threadIdx.x < range) cnt[lo + threadIdx.x] = myc;
    lscan[threadIdx.x] = myc;
    __syncthreads();
    for (int off = 1; off < 1024; off <<= 1) {
        int y = (threadIdx.x >= off) ? lscan[threadIdx.x - off] : 0;
        __syncthreads();
        lscan[threadIdx.x] += y;
        __syncthreads();
    }
    int colbase = b * cap;
    int excl = lscan[threadIdx.x] - myc;
    if ((int)threadIdx.x < range) rowstart[lo + threadIdx.x] = colbase + excl;
    lcnt[threadIdx.x] = excl;                 // reuse as cursors
    __syncthreads();
    for (int i = threadIdx.x; i < n; i += 1024) {
        int2 v = bk[i];
        int pos = atomicAdd(&lcnt[v.y - lo], 1);
        col[(size_t)colbase + pos] = v.x;
    }
}

// dinv, xs (x*dinv f32), and Abf2 cols 0..7 = bf16(x) + zero tail cols 136..159
__global__ __launch_bounds__(256) void dinv_xs_kernel(const int* __restrict__ cnt,
                                                      const float* __restrict__ x,
                                                      float* __restrict__ dinv,
                                                      float* __restrict__ xs,
                                                      unsigned short* __restrict__ Abf2,
                                                      int n) {
    int v = blockIdx.x * 256 + threadIdx.x;
    if (v >= n) return;
    float dv = rsqrtf((float)(cnt[v] + 1));
    dinv[v] = dv;
    const float4* x4 = (const float4*)x;
    float4 a = x4[v * 2], b = x4[v * 2 + 1];
    float4* o = (float4*)xs;
    o[v * 2]     = make_float4(a.x * dv, a.y * dv, a.z * dv, a.w * dv);
    o[v * 2 + 1] = make_float4(b.x * dv, b.y * dv, b.z * dv, b.w * dv);
    unsigned short u[8] = {f32_to_bf16_rne(a.x), f32_to_bf16_rne(a.y),
                           f32_to_bf16_rne(a.z), f32_to_bf16_rne(a.w),
                           f32_to_bf16_rne(b.x), f32_to_bf16_rne(b.y),
                           f32_to_bf16_rne(b.z), f32_to_bf16_rne(b.w)};
    ulonglong2 pk;
    pk.x = (unsigned long long)u[0] | ((unsigned long long)u[1] << 16)
         | ((unsigned long long)u[2] << 32) | ((unsigned long long)u[3] << 48);
    pk.y = (unsigned long long)u[4] | ((unsigned long long)u[5] << 16)
         | ((unsigned long long)u[6] << 32) | ((unsigned long long)u[7] << 48);
    *(ulonglong2*)&Abf2[(size_t)v * 160] = pk;
    ulonglong2 z; z.x = 0ull; z.y = 0ull;
    *(ulonglong2*)&Abf2[(size_t)v * 160 + 136] = z;
    *(ulonglong2*)&Abf2[(size_t)v * 160 + 144] = z;
    *(ulonglong2*)&Abf2[(size_t)v * 160 + 152] = z;
}

// agg over 8 features; writes f32 aggx (c1 input) AND bf16 into Abf cols 128..135
// + zero tail cols 136..159.
__global__ __launch_bounds__(256) void agg8_kernel(const float* __restrict__ xs,
                                                   const int* __restrict__ rowstart,
                                                   const int* __restrict__ cnt,
                                                   const int* __restrict__ col,
                                                   const float* __restrict__ dinv,
                                                   float* __restrict__ aggx,
                                                   unsigned short* __restrict__ Abf,
                                                   int n) {
    int v = blockIdx.x * 256 + threadIdx.x;
    if (v >= n) return;
    const float4* r4 = (const float4*)xs;
    float4 a = make_float4(0, 0, 0, 0), b = make_float4(0, 0, 0, 0);
    int start = rowstart[v];
    int end = start + cnt[v];
    for (int j = start; j < end; j++) {
        int s = col[j];
        float4 p = r4[(size_t)s * 2], q = r4[(size_t)s * 2 + 1];
        a.x += p.x; a.y += p.y; a.z += p.z; a.w += p.w;
        b.x += q.x; b.y += q.y; b.z += q.z; b.w += q.w;
    }
    float4 p = r4[(size_t)v * 2], q = r4[(size_t)v * 2 + 1];
    a.x += p.x; a.y += p.y; a.z += p.z; a.w += p.w;
    b.x += q.x; b.y += q.y; b.z += q.z; b.w += q.w;
    float dv = dinv[v];
    a = make_float4(a.x * dv, a.y * dv, a.z * dv, a.w * dv);
    b = make_float4(b.x * dv, b.y * dv, b.z * dv, b.w * dv);
    float4* o = (float4*)aggx;
    o[(size_t)v * 2]     = a;
    o[(size_t)v * 2 + 1] = b;
    unsigned short u[8] = {f32_to_bf16_rne(a.x), f32_to_bf16_rne(a.y),
                           f32_to_bf16_rne(a.z), f32_to_bf16_rne(a.w),
                           f32_to_bf16_rne(b.x), f32_to_bf16_rne(b.y),
                           f32_to_bf16_rne(b.z), f32_to_bf16_rne(b.w)};
    ulonglong2 pk;
    pk.x = (unsigned long long)u[0] | ((unsigned long long)u[1] << 16)
         | ((unsigned long long)u[2] << 32) | ((unsigned long long)u[3] << 48);
    pk.y = (unsigned long long)u[4] | ((unsigned long long)u[5] << 16)
         | ((unsigned long long)u[6] << 32) | ((unsigned long long)u[7] << 48);
    *(ulonglong2*)&Abf[(size_t)v * 160 + 128] = pk;
    ulonglong2 z; z.x = 0ull; z.y = 0ull;
    *(ulonglong2*)&Abf[(size_t)v * 160 + 136] = z;
    *(ulonglong2*)&Abf[(size_t)v * 160 + 144] = z;
    *(ulonglong2*)&Abf[(size_t)v * 160 + 152] = z;
}

// agg over 128 bf16 features: one wave per node; writes bf16 into Abf cols 0..127
__global__ __launch_bounds__(256) void agg128_kernel(const unsigned* __restrict__ rows,
                                                     const int* __restrict__ rowstart,
                                                     const int* __restrict__ cnt,
                                                     const int* __restrict__ col,
                                                     const float* __restrict__ dinv,
                                                     unsigned short* __restrict__ Abf,
                                                     int n) {
    int v = blockIdx.x * 4 + (threadIdx.x >> 6);
    int lane = threadIdx.x & 63;
    if (v >= n) return;
    float ax = 0.f, ay = 0.f;
    int start = rowstart[v];
    int end = start + cnt[v];
    for (int base = start; base < end; base += 64) {
        int m = end - base; if (m > 64) m = 64;
        int si = (lane < m) ? col[base + lane] : 0;
        int t = 0;
        for (; t + 4 <= m; t += 4) {
            int s0 = __shfl(si, t),     s1 = __shfl(si, t + 1);
            int s2 = __shfl(si, t + 2), s3 = __shfl(si, t + 3);
            unsigned u0 = rows[(size_t)s0 * 64 + lane];
            unsigned u1 = rows[(size_t)s1 * 64 + lane];
            unsigned u2 = rows[(size_t)s2 * 64 + lane];
            unsigned u3 = rows[(size_t)s3 * 64 + lane];
            ax += (__uint_as_float(u0 << 16) + __uint_as_float(u1 << 16))
                + (__uint_as_float(u2 << 16) + __uint_as_float(u3 << 16));
            ay += (__uint_as_float(u0 & 0xffff0000u) + __uint_as_float(u1 & 0xffff0000u))
                + (__uint_as_float(u2 & 0xffff0000u) + __uint_as_float(u3 & 0xffff0000u));
        }
        for (; t < m; t++) {
            int s = __shfl(si, t);
            unsigned u = rows[(size_t)s * 64 + lane];
            ax += __uint_as_float(u << 16);
            ay += __uint_as_float(u & 0xffff0000u);
        }
    }
    unsigned us = rows[(size_t)v * 64 + lane];
    ax += __uint_as_float(us << 16);
    ay += __uint_as_float(us & 0xffff0000u);
    float dv = dinv[v];
    unsigned pk = (unsigned)f32_to_bf16_rne(ax * dv)
                | ((unsigned)f32_to_bf16_rne(ay * dv) << 16);
    ((unsigned*)Abf)[(size_t)v * 80 + lane] = pk;
}

// c1 layer (K=8), fp32 VALU: h1s = bf16(relu(aggx @ c1W + c1b) * dinv)
__global__ __launch_bounds__(256) void gemm8_kernel(
    const float* __restrict__ A1, const float* __restrict__ W,
    const float* __restrict__ bias, const float* __restrict__ dinv,
    unsigned short* __restrict__ out, int n) {
    constexpr int K = 8, KP = 12, NPB = 32;
    __shared__ float lds[NPB * KP];
    int node0 = blockIdx.x * NPB;
    for (int idx = threadIdx.x; idx < NPB * K; idx += 256) {
        int r = idx / K, k = idx - r * K;
        int node = node0 + r;
        lds[r * KP + k] = (node < n) ? A1[(size_t)node * K + k] : 0.f;
    }
    __syncthreads();
    int f8 = threadIdx.x & 15, ng = threadIdx.x >> 4;
    int fbase = f8 * 8;
    float acc[2][8];
#pragma unroll
    for (int r = 0; r < 2; r++)
#pragma unroll
        for (int j = 0; j < 8; j++) acc[r][j] = 0.f;
    for (int k = 0; k < K; k += 4) {
        float4 wlo[4], whi[4];
#pragma unroll
        for (int kk = 0; kk < 4; kk++) {
            wlo[kk] = *(const float4*)&W[(size_t)(k + kk) * 128 + fbase];
            whi[kk] = *(const float4*)&W[(size_t)(k + kk) * 128 + fbase + 4];
        }
#pragma unroll
        for (int r = 0; r < 2; r++) {
            float4 a = *(const float4*)&lds[(2 * ng + r) * KP + k];
            float av[4] = {a.x, a.y, a.z, a.w};
#pragma unroll
            for (int kk = 0; kk < 4; kk++) {
                acc[r][0] += av[kk] * wlo[kk].x; acc[r][1] += av[kk] * wlo[kk].y;
                acc[r][2] += av[kk] * wlo[kk].z; acc[r][3] += av[kk] * wlo[kk].w;
                acc[r][4] += av[kk] * whi[kk].x; acc[r][5] += av[kk] * whi[kk].y;
                acc[r][6] += av[kk] * whi[kk].z; acc[r][7] += av[kk] * whi[kk].w;
            }
        }
    }
    float4 blo = *(const float4*)&bias[fbase];
    float4 bhi = *(const float4*)&bias[fbase + 4];
    float bv[8] = {blo.x, blo.y, blo.z, blo.w, bhi.x, bhi.y, bhi.z, bhi.w};
#pragma unroll
    for (int r = 0; r < 2; r++) {
        int node = node0 + 2 * ng + r;
        if (node < n) {
            float dv = dinv[node];
            unsigned short u[8];
#pragma unroll
            for (int j = 0; j < 8; j++)
                u[j] = f32_to_bf16_rne(fmaxf(acc[r][j] + bv[j], 0.f) * dv);
            ulonglong2 pk;
            pk.x = (unsigned long long)u[0] | ((unsigned long long)u[1] << 16)
                 | ((unsigned long long)u[2] << 32) | ((unsigned long long)u[3] << 48);
            pk.y = (unsigned long long)u[4] | ((unsigned long long)u[5] << 16)
                 | ((unsigned long long)u[6] << 32) | ((unsigned long long)u[7] << 48);
            *(ulonglong2*)&out[(size_t)node * 128 + fbase] = pk;
        }
    }
}

// Pack W[K x 128] f32 (K<=136) into MFMA B-fragment layout, K padded to 160
__global__ __launch_bounds__(256) void pack_w_kernel(const float* __restrict__ W,
                                                     unsigned short* __restrict__ wp, int K) {
    int t = blockIdx.x * 256 + threadIdx.x;
    if (t >= 20480) return;
    int i = t & 7, l = (t >> 3) & 63, fc = (t >> 9) & 7, ks = t >> 12;
    int k = ks * 32 + (l >> 4) * 8 + i;
    int c = (l & 15) + 16 * fc;
    float v = (k < K) ? W[(size_t)k * 128 + c] : 0.f;
    wp[t] = f32_to_bf16_rne(v);
}

// MFMA GEMM: C[N x 128] = A[N x 160 bf16] @ Wpack (+bias, relu)
// MODE 1: store bf16 h2 into Abf2 cols 8..135 (row stride 160)
// MODE 2: fused f5: out[row] = sigmoid(x[row]·f5W[0:8] + h4·f5W[8:136] + f5b)
template <int MODE>
__global__ __launch_bounds__(256) void mfma_gemm(
    const unsigned short* __restrict__ A, const unsigned short* __restrict__ wp,
    const float* __restrict__ bias, const float* __restrict__ x,
    const float* __restrict__ f5W, const float* __restrict__ f5b,
    void* __restrict__ outv, int n) {
    __shared__ float ldsx[64];
    int node0 = blockIdx.x * 64;
    if constexpr (MODE == 2) {
        if (threadIdx.x < 64) {
            int rc = min(node0 + (int)threadIdx.x, n - 1);
            float s = 0.f;
#pragma unroll
            for (int k = 0; k < 8; k++) s += x[(size_t)rc * 8 + k] * f5W[k];
            ldsx[threadIdx.x] = s;
        }
        __syncthreads();
    }
    int wave = threadIdx.x >> 6, lane = threadIdx.x & 63;
    int g = lane >> 4, r = lane & 15;
    int row0 = node0 + wave * 16;
    int arow = min(row0 + r, n - 1);

    short8 a[5];
#pragma unroll
    for (int ks = 0; ks < 5; ks++)
        a[ks] = *(const short8*)&A[(size_t)arow * 160 + ks * 32 + g * 8];

    f32x4 acc[8] = {};
#pragma unroll
    for (int ks = 0; ks < 5; ks++) {
#pragma unroll
        for (int fc = 0; fc < 8; fc++) {
            short8 w = *(const short8*)&wp[(size_t)((ks * 8 + fc) * 64 + lane) * 8];
            acc[fc] = __builtin_amdgcn_mfma_f32_16x16x32_bf16(a[ks], w, acc[fc], 0, 0, 0);
        }
    }

    if constexpr (MODE == 1) {
        unsigned short* out = (unsigned short*)outv;
#pragma unroll
        for (int fc = 0; fc < 8; fc++) {
            int c = r + 16 * fc;
            float bc = bias[c];
#pragma unroll
            for (int v = 0; v < 4; v++) {
                int row = row0 + 4 * g + v;
                if (row < n)
                    out[(size_t)row * 160 + 8 + c] =
                        f32_to_bf16_rne(fmaxf(acc[fc][v] + bc, 0.f));
            }
        }
    } else {
        float plog[4] = {0.f, 0.f, 0.f, 0.f};
#pragma unroll
        for (int fc = 0; fc < 8; fc++) {
            int c = r + 16 * fc;
            float bc = bias[c];
            float w5 = f5W[8 + c];
#pragma unroll
            for (int v = 0; v < 4; v++)
                plog[v] += fmaxf(acc[fc][v] + bc, 0.f) * w5;
        }
#pragma unroll
        for (int m = 1; m < 16; m <<= 1) {
#pragma unroll
            for (int v = 0; v < 4; v++) plog[v] += __shfl_xor(plog[v], m);
        }
        if (r == 0) {
            float* out = (float*)outv;
            float fb = f5b[0];
#pragma unroll
            for (int v = 0; v < 4; v++) {
                int row = row0 + 4 * g + v;
                if (row < n)
                    out[row] = 1.f / (1.f + expf(-(plog[v] + ldsx[wave * 16 + 4 * g + v] + fb)));
            }
        }
    }
}

extern "C" void kernel_launch(void* const* d_in, const int* in_sizes, int n_in,
                              void* d_out, int out_size, void* d_ws, size_t ws_size,
                              hipStream_t stream) {
    const float* x   = (const float*)d_in[0];
    const int*   ei  = (const int*)d_in[1];
    const float* c1W = (const float*)d_in[2];
    const float* c1b = (const float*)d_in[3];
    const float* c2W = (const float*)d_in[4];
    const float* c2b = (const float*)d_in[5];
    const float* f4W = (const float*)d_in[18];
    const float* f4b = (const float*)d_in[19];
    const float* f5W = (const float*)d_in[20];
    const float* f5b = (const float*)d_in[21];
    float* out = (float*)d_out;

    int N = in_sizes[0] / 8;
    int E = in_sizes[1] / 2;

    char* p = (char*)d_ws;
    auto alloc = [&](size_t bytes) {
        char* q = p;
        p += (bytes + 255) & ~(size_t)255;
        return q;
    };
    const int cap = 14000;                      // per-bucket capacity (E/128 ~12.5K)
    int*            cnt      = (int*)alloc((size_t)N * 4);
    int*            rowstart = (int*)alloc((size_t)N * 4);
    int*            bcnt_pad = (int*)alloc(NBUK * 16 * 4);     // line-padded
    float*          dinv     = (float*)alloc((size_t)N * 4);
    int*            col      = (int*)alloc((size_t)NBUK * cap * 4);   // 7.2MB
    float*          xs       = (float*)alloc((size_t)N * 8 * 4);
    float*          aggx     = (float*)alloc((size_t)N * 8 * 4);
    unsigned short* bufH1    = (unsigned short*)alloc((size_t)N * 128 * 2); // h1s bf16
    unsigned short* Abf      = (unsigned short*)alloc((size_t)N * 160 * 2); // [aggh1|aggx|0]
    unsigned short* Abf2     = (unsigned short*)alloc((size_t)N * 160 * 2); // [x|h2|0]
    unsigned short* wp2      = (unsigned short*)alloc(20480 * 2);
    unsigned short* wp4      = (unsigned short*)alloc(20480 * 2);

    // bucket (14.3MB) aliases bufH1 (25.6MB): consumed by csr_kernel before
    // gemm8 writes bufH1 (stream-ordered).
    int2* bucket = (int2*)bufH1;

    (void)hipMemsetAsync(bcnt_pad, 0, NBUK * 16 * 4, stream);

    int gN = (N + 255) / 256;
    pack_w_kernel<<<80, 256, 0, stream>>>(c2W, wp2, 136);
    pack_w_kernel<<<80, 256, 0, stream>>>(f4W, wp4, 136);

    // Phase 1: 128-way bucket (one ei pass, LDS-atomic ranking)
    int gB = (E + 8191) / 8192;
    bucket_kernel<<<gB, 512, 0, stream>>>(ei, bcnt_pad, bucket, E, N, cap);

    // Phase 2: fused per-bucket count + scan + fill (no global atomics)
    csr_kernel<<<NBUK, 1024, 0, stream>>>(bucket, bcnt_pad, cnt, rowstart, col, N, cap);

    dinv_xs_kernel<<<gN, 256, 0, stream>>>(cnt, x, dinv, xs, Abf2, N);

    agg8_kernel<<<gN, 256, 0, stream>>>(xs, rowstart, cnt, col, dinv, aggx, Abf, N);

    // h1s = bf16( relu(aggx @ c1W + c1b) * dinv )
    gemm8_kernel<<<(N + 31) / 32, 256, 0, stream>>>(aggx, c1W, c1b, dinv, bufH1, N);

    // aggh1 (bf16) into Abf cols 0..127
    agg128_kernel<<<(N + 3) / 4, 256, 0, stream>>>((const unsigned*)bufH1, rowstart,
                                                   cnt, col, dinv, Abf, N);

    int g64 = (N + 63) / 64;
    // h2 = relu([aggh1, aggx] @ c2W + c2b) -> bf16 into Abf2 cols 8..135
    mfma_gemm<1><<<g64, 256, 0, stream>>>(Abf, wp2, c2b, nullptr, nullptr, nullptr,
                                          Abf2, N);
    // h4 = relu([x, h2] @ f4W + f4b); out = sigmoid([x, h4] @ f5W + f5b)
    mfma_gemm<2><<<g64, 256, 0, stream>>>(Abf2, wp4, f4b, x, f5W, f5b, out, N);
}